// Round 24
// baseline (42.611 us; speedup 1.0000x reference)
//
#include <hip/hip_runtime.h>
#include <cfloat>

typedef float f32x16 __attribute__((ext_vector_type(16)));
typedef short s16x8  __attribute__((ext_vector_type(8)));

// Problem constants
constexpr int B = 4, N = 8192;
constexpr int JT   = 8;              // 32-col j-tiles per wave (output side)
constexpr int JSTR = N / (32 * JT);  // 32 j-strips
constexpr int IGR  = 64;             // 128-row i-groups (4 waves x 32 rows)
constexpr int NSEG = 2 * B;          // 8 (dir,b) segments

__device__ __forceinline__ unsigned short f2bf(float x) {   // RNE bf16
    unsigned int u = __float_as_uint(x);
    u += 0x7fffu + ((u >> 16) & 1u);
    return (unsigned short)(u >> 16);
}
__device__ __forceinline__ float bf2f(unsigned short h) {
    return __uint_as_float((unsigned int)h << 16);
}

// Pack each point into BOTH operand forms (validated slot plan, R7-R23):
//   A-form row: [-2xh,-2yh,-2zh, -2xl,-2yl,-2zl, -2xh,-2yh | -2zh, 1, 1, nh, nl, 0,0,0]
//   B-form col: [  xh,  yh,  zh,   xh,  yh,  zh,   xl,  yl |   zl, nh, nl, 1, 1, 0,0,0]
// => MFMA c = nA + nB - 2*a.b (squared distance; ll term dropped, err ~1e-3)
// Fragment layout (32x32x16): lane holds (row|col)=lane&31, k = 8*(lane>>5)+kk.
__global__ __launch_bounds__(256) void pack_kernel(
        const float* __restrict__ pred, const float* __restrict__ gt,
        uint4* __restrict__ Aform, uint4* __restrict__ Bform) {
    int id    = blockIdx.x * 256 + threadIdx.x;  // [0, 131072)
    int cloud = id >> 16;                        // 0 = pred, 1 = gt
    int rem   = id & 65535;
    int b     = rem >> 14;
    int t2    = rem & 16383;
    int blk   = t2 >> 6;                         // 32-point block [0,256)
    int lane  = t2 & 63;
    int h     = lane >> 5;
    int row   = blk * 32 + (lane & 31);

    const float* s = (cloud ? gt : pred) + ((size_t)b * N + row) * 3;
    float x = s[0], y = s[1], z = s[2];
    unsigned short xh = f2bf(x), yh = f2bf(y), zh = f2bf(z);
    float xl = x - bf2f(xh), yl = y - bf2f(yh), zl = z - bf2f(zh);
    float n = fmaf(x, x, fmaf(y, y, z * z));
    unsigned short nh = f2bf(n);
    unsigned short nl = f2bf(n - bf2f(nh));
    const unsigned short ONE = 0x3F80;

    unsigned short wa[8], wb[8];
    unsigned short mxh = f2bf(-2.f * bf2f(xh));
    unsigned short myh = f2bf(-2.f * bf2f(yh));
    unsigned short mzh = f2bf(-2.f * bf2f(zh));
    if (h == 0) {
        wa[0] = mxh; wa[1] = myh; wa[2] = mzh;
        wa[3] = f2bf(-2.f * xl); wa[4] = f2bf(-2.f * yl); wa[5] = f2bf(-2.f * zl);
        wa[6] = mxh; wa[7] = myh;
        wb[0] = xh; wb[1] = yh; wb[2] = zh;
        wb[3] = xh; wb[4] = yh; wb[5] = zh;
        wb[6] = f2bf(xl); wb[7] = f2bf(yl);
    } else {
        wa[0] = mzh; wa[1] = ONE; wa[2] = ONE; wa[3] = nh; wa[4] = nl;
        wa[5] = 0; wa[6] = 0; wa[7] = 0;
        wb[0] = f2bf(zl); wb[1] = nh; wb[2] = nl; wb[3] = ONE; wb[4] = ONE;
        wb[5] = 0; wb[6] = 0; wb[7] = 0;
    }
    uint4 oa, ob;
    oa.x = (unsigned)wa[0] | ((unsigned)wa[1] << 16);
    oa.y = (unsigned)wa[2] | ((unsigned)wa[3] << 16);
    oa.z = (unsigned)wa[4] | ((unsigned)wa[5] << 16);
    oa.w = (unsigned)wa[6] | ((unsigned)wa[7] << 16);
    ob.x = (unsigned)wb[0] | ((unsigned)wb[1] << 16);
    ob.y = (unsigned)wb[2] | ((unsigned)wb[3] << 16);
    ob.z = (unsigned)wb[4] | ((unsigned)wb[5] << 16);
    ob.w = (unsigned)wb[6] | ((unsigned)wb[7] << 16);
    size_t off = (((size_t)cloud * B + b) * 256 + blk) * 64 + lane;
    Aform[off] = oa;
    Bform[off] = ob;
}

// OCCUPANCY-8 variant of the R23 winner (R23: (256,4) cap-128 gave 45.4->40.5).
// Next m69 bin needs <=64 VGPR: IB=1 (one C-tile: 16 + zc 16 + afr 4 + bfr 8
// + addr ~12 ~ 56 regs). Latency hiding moves from 4-chain ILP to 8-wave TLP;
// total VALU work (524k tiles x same scalar tree) is unchanged. The per-jt
// __shfl_xor (LDS-pipe bpermute) is deleted: both lane-halves write their
// 16-row partial mins to scm[8][256] (2-way bank = free), one post-loop fold
// writes part (same 8 MB shape as R23 -> reduce1 unchanged). No manual LDS
// prefetch: 8 waves/SIMD hide the ~120cyc ds_read.
__global__ __launch_bounds__(256, 8) void chamfer_mfma(
        const uint4* __restrict__ Aform, const uint4* __restrict__ Bform,
        unsigned short* __restrict__ part) {
    int bid = blockIdx.x;
    int js  = bid & (JSTR - 1);        // fastest: consecutive blocks share A panel
    int r   = bid >> 5;
    int ig  = r & (IGR - 1); r >>= 6;  // 128-row i-group
    int b   = r & 3;
    int dir = r >> 2;                  // 0: minimize over pred; 1: over gt
    int Acl = dir;                     // A-side cloud (rows, minimized over)
    int Bcl = dir ^ 1;                 // B-side cloud (cols, output)

    int w    = threadIdx.x >> 6;
    int lane = threadIdx.x & 63;
    int is   = ig * 4 + w;             // [0,256): this wave's 32-row strip

    // Shared B-tile (8 KB) + per-halfwave partial col-mins (8 KB).
    __shared__ uint4 sb[JT * 64];
    __shared__ float scm[8][JT * 32];
    const uint4* bblk = Bform + (((size_t)Bcl * B + b) * 256 + js * JT) * 64;
    sb[threadIdx.x]       = bblk[threadIdx.x];
    sb[threadIdx.x + 256] = bblk[threadIdx.x + 256];

    // This wave's single A fragment (32 rows).
    s16x8 afr = __builtin_bit_cast(s16x8,
        Aform[(((size_t)Acl * B + b) * 256 + is) * 64 + lane]);

    __syncthreads();

    const f32x16 zc = {};
    int srow = w * 2 + (lane >> 5);    // [0,8): half-wave partial row
    int scol = lane & 31;

#pragma unroll 1
    for (int jt = 0; jt < JT; ++jt) {
        s16x8 bfr = __builtin_bit_cast(s16x8, sb[jt * 64 + lane]);
        f32x16 c = __builtin_amdgcn_mfma_f32_32x32x16_bf16(afr, bfr, zc, 0, 0, 0);
        // scalar min tree over this lane's 16 rows (v_min3 fusion)
        float u0 = fminf(fminf(c[0], c[1]), c[2]);
        float u1 = fminf(fminf(c[3], c[4]), c[5]);
        float u2 = fminf(fminf(c[6], c[7]), c[8]);
        float u3 = fminf(fminf(c[9], c[10]), c[11]);
        float u4 = fminf(fminf(c[12], c[13]), c[14]);
        float m  = fminf(fminf(u0, u1), fminf(fminf(u2, u3), fminf(u4, c[15])));
        scm[srow][jt * 32 + scol] = m;   // full 64-lane store, no shuffle
    }
    __syncthreads();

    // Fold the 8 half-wave partials -> 256 col-mins of this 128-row i-group.
    {
        int col = threadIdx.x;           // [0,256)
        float v = scm[0][col];
#pragma unroll
        for (int q = 1; q < 8; ++q) v = fminf(v, scm[q][col]);
        unsigned short* po = part + (((size_t)dir * B + b) * IGR + ig) * N
                           + js * (JT * 32) + col;
        *po = f2bf(v);
    }
}

// 256 blocks: seg = bk>>5; min over 64 i-groups -> block sum/max partials.
__global__ __launch_bounds__(256) void reduce1(
        const unsigned short* __restrict__ part,
        float* __restrict__ bsum, float* __restrict__ bmax) {
    int bk  = blockIdx.x;
    int seg = bk >> 5;                 // 0..7
    int idx = (bk & 31) * 256 + threadIdx.x;
    const unsigned short* base = part + (size_t)seg * IGR * N + idx;
    float v = FLT_MAX;
#pragma unroll 8
    for (int s = 0; s < IGR; ++s)
        v = fminf(v, bf2f(base[(size_t)s * N]));
    __shared__ float ssum[256], smax[256];
    ssum[threadIdx.x] = v;
    smax[threadIdx.x] = v;
    __syncthreads();
    for (int st = 128; st > 0; st >>= 1) {
        if (threadIdx.x < st) {
            ssum[threadIdx.x] += ssum[threadIdx.x + st];
            smax[threadIdx.x] = fmaxf(smax[threadIdx.x], smax[threadIdx.x + st]);
        }
        __syncthreads();
    }
    if (threadIdx.x == 0) { bsum[bk] = ssum[0]; bmax[bk] = smax[0]; }
}

// Combine 256 block partials. Blocks [seg*32, seg*32+32) belong to segment seg.
__global__ __launch_bounds__(256) void final_combine(
        const float* __restrict__ bsum, const float* __restrict__ bmax,
        float* __restrict__ out) {
    int t = threadIdx.x;
    __shared__ float ss[256], sm[256];
    ss[t] = bsum[t];
    sm[t] = bmax[t];
    __syncthreads();
    for (int st = 128; st > 0; st >>= 1) {
        if (t < st) ss[t] += ss[t + st];
        __syncthreads();
    }
    for (int st = 16; st > 0; st >>= 1) {
        if ((t & 31) < st) sm[t] = fmaxf(sm[t], sm[t + st]);
        __syncthreads();
    }
    if (t == 0) {
        float hsum = 0.f;
#pragma unroll
        for (int k = 0; k < NSEG; ++k) hsum += sm[k * 32];
        out[0] = ss[0] / (float)(B * N);   // chamfer
        out[1] = hsum / (float)B;          // hausdorff
    }
}

extern "C" void kernel_launch(void* const* d_in, const int* in_sizes, int n_in,
                              void* d_out, int out_size, void* d_ws, size_t ws_size,
                              hipStream_t stream) {
    const float* pred = (const float*)d_in[0];
    const float* gt   = (const float*)d_in[1];
    float* out = (float*)d_out;

    char* p = (char*)d_ws;
    uint4* Aform = (uint4*)p;  p += (size_t)2 * B * 256 * 64 * 16;   // 2 MB
    uint4* Bform = (uint4*)p;  p += (size_t)2 * B * 256 * 64 * 16;   // 2 MB
    unsigned short* part = (unsigned short*)p;
    p += (size_t)NSEG * IGR * N * 2;                                 // 8 MB
    float* bsum = (float*)p;   p += 256 * 4;
    float* bmax = (float*)p;

    pack_kernel<<<512, 256, 0, stream>>>(pred, gt, Aform, Bform);
    // blocks: dir(2) x b(4) x ig(64) x js(32) = 16384, 4 waves each
    chamfer_mfma<<<16384, 256, 0, stream>>>(Aform, Bform, part);
    reduce1<<<256, 256, 0, stream>>>(part, bsum, bmax);
    final_combine<<<1, 256, 0, stream>>>(bsum, bmax, out);
}

// Round 25
// 33.671 us; speedup vs baseline: 1.2655x; 1.2655x over previous
//
#include <hip/hip_runtime.h>
#include <cfloat>

typedef float f32x16 __attribute__((ext_vector_type(16)));
typedef short s16x8  __attribute__((ext_vector_type(8)));

// Problem constants
constexpr int B = 4, N = 8192;
constexpr int IB   = 4;              // 32-row i-blocks per wave (minimized-over side)
constexpr int JT   = 8;              // 32-col j-tiles per wave (output side)
constexpr int IGR  = 16;             // 512-row i-groups (4 waves x 128 rows) per (dir,b)
constexpr int JSTR = N / (32 * JT);  // 32 j-strips
constexpr int NSEG = 2 * B;          // 8 (dir,b) segments

__device__ __forceinline__ unsigned short f2bf(float x) {   // RNE bf16
    unsigned int u = __float_as_uint(x);
    u += 0x7fffu + ((u >> 16) & 1u);
    return (unsigned short)(u >> 16);
}
__device__ __forceinline__ float bf2f(unsigned short h) {
    return __uint_as_float((unsigned int)h << 16);
}

// Pack each point into BOTH operand forms (validated slot plan, R7-R24):
//   A-form row: [-2xh,-2yh,-2zh, -2xl,-2yl,-2zl, -2xh,-2yh | -2zh, 1, 1, nh, nl, 0,0,0]
//   B-form col: [  xh,  yh,  zh,   xh,  yh,  zh,   xl,  yl |   zl, nh, nl, 1, 1, 0,0,0]
// => MFMA c = nA + nB - 2*a.b (squared distance; ll term dropped, err ~1e-3)
// Fragment layout (32x32x16): lane holds (row|col)=lane&31, k = 8*(lane>>5)+kk.
__global__ __launch_bounds__(256) void pack_kernel(
        const float* __restrict__ pred, const float* __restrict__ gt,
        uint4* __restrict__ Aform, uint4* __restrict__ Bform) {
    int id    = blockIdx.x * 256 + threadIdx.x;  // [0, 131072)
    int cloud = id >> 16;                        // 0 = pred, 1 = gt
    int rem   = id & 65535;
    int b     = rem >> 14;
    int t2    = rem & 16383;
    int blk   = t2 >> 6;                         // 32-point block [0,256)
    int lane  = t2 & 63;
    int h     = lane >> 5;
    int row   = blk * 32 + (lane & 31);

    const float* s = (cloud ? gt : pred) + ((size_t)b * N + row) * 3;
    float x = s[0], y = s[1], z = s[2];
    unsigned short xh = f2bf(x), yh = f2bf(y), zh = f2bf(z);
    float xl = x - bf2f(xh), yl = y - bf2f(yh), zl = z - bf2f(zh);
    float n = fmaf(x, x, fmaf(y, y, z * z));
    unsigned short nh = f2bf(n);
    unsigned short nl = f2bf(n - bf2f(nh));
    const unsigned short ONE = 0x3F80;

    unsigned short wa[8], wb[8];
    unsigned short mxh = f2bf(-2.f * bf2f(xh));
    unsigned short myh = f2bf(-2.f * bf2f(yh));
    unsigned short mzh = f2bf(-2.f * bf2f(zh));
    if (h == 0) {
        wa[0] = mxh; wa[1] = myh; wa[2] = mzh;
        wa[3] = f2bf(-2.f * xl); wa[4] = f2bf(-2.f * yl); wa[5] = f2bf(-2.f * zl);
        wa[6] = mxh; wa[7] = myh;
        wb[0] = xh; wb[1] = yh; wb[2] = zh;
        wb[3] = xh; wb[4] = yh; wb[5] = zh;
        wb[6] = f2bf(xl); wb[7] = f2bf(yl);
    } else {
        wa[0] = mzh; wa[1] = ONE; wa[2] = ONE; wa[3] = nh; wa[4] = nl;
        wa[5] = 0; wa[6] = 0; wa[7] = 0;
        wb[0] = f2bf(zl); wb[1] = nh; wb[2] = nl; wb[3] = ONE; wb[4] = ONE;
        wb[5] = 0; wb[6] = 0; wb[7] = 0;
    }
    uint4 oa, ob;
    oa.x = (unsigned)wa[0] | ((unsigned)wa[1] << 16);
    oa.y = (unsigned)wa[2] | ((unsigned)wa[3] << 16);
    oa.z = (unsigned)wa[4] | ((unsigned)wa[5] << 16);
    oa.w = (unsigned)wa[6] | ((unsigned)wa[7] << 16);
    ob.x = (unsigned)wb[0] | ((unsigned)wb[1] << 16);
    ob.y = (unsigned)wb[2] | ((unsigned)wb[3] << 16);
    ob.z = (unsigned)wb[4] | ((unsigned)wb[5] << 16);
    ob.w = (unsigned)wb[6] | ((unsigned)wb[7] << 16);
    size_t off = (((size_t)cloud * B + b) * 256 + blk) * 64 + lane;
    Aform[off] = oa;
    Bform[off] = ob;
}

// R23 winner (IB=4, (256,4) cap-128 -> 4 waves/SIMD, rolled jt, depth-1 LDS
// prefetch, 4 MFMA -> scalar-min-tree chains) with ONE change: the per-jt
// __shfl_xor (ds_bpermute + wait + fmin + divergent store — a serial tail on
// every jt) is replaced by a fire-and-forget scm LDS write (64 lanes,
// bank-clean). A single post-loop fold collapses the block's 8 half-wave
// partials (4 waves x 2 halves, each = min over 64 rows) into one 512-row
// col-min -> part shrinks 8 MB -> 2 MB (reduce1 reads 4x less).
__global__ __launch_bounds__(256, 4) void chamfer_mfma(
        const uint4* __restrict__ Aform, const uint4* __restrict__ Bform,
        unsigned short* __restrict__ part) {
    int bid = blockIdx.x;
    int js  = bid & (JSTR - 1);        // fastest: consecutive blocks share A panel
    int r   = bid >> 5;
    int is4 = r & 15; r >>= 4;
    int b   = r & 3;
    int dir = r >> 2;                  // 0: minimize over pred; 1: over gt
    int Acl = dir;                     // A-side cloud (rows, minimized over)
    int Bcl = dir ^ 1;                 // B-side cloud (cols, output)

    int w    = threadIdx.x >> 6;
    int lane = threadIdx.x & 63;
    int is   = is4 * 4 + w;

    // Shared B-tile (8 KB) + half-wave partial col-mins (8 KB).
    __shared__ uint4 sb[JT * 64];
    __shared__ float scm[8][JT * 32];
    const uint4* bblk = Bform + (((size_t)Bcl * B + b) * 256 + js * JT) * 64;
    sb[threadIdx.x]       = bblk[threadIdx.x];
    sb[threadIdx.x + 256] = bblk[threadIdx.x + 256];

    // Per-wave A fragments (issued before the barrier to overlap latency).
    const uint4* ablk = Aform + (((size_t)Acl * B + b) * 256 + is * IB) * 64 + lane;
    s16x8 afr[IB];
#pragma unroll
    for (int ib = 0; ib < IB; ++ib)
        afr[ib] = __builtin_bit_cast(s16x8, ablk[(size_t)ib * 64]);

    __syncthreads();

    const f32x16 zc = {};
    int srow = w * 2 + (lane >> 5);    // [0,8): half-wave partial row
    int scol = lane & 31;

    s16x8 bnext = __builtin_bit_cast(s16x8, sb[lane]);   // jt=0 fragment
#pragma unroll 1
    for (int jt = 0; jt < JT; ++jt) {
        s16x8 bfr = bnext;
        if (jt + 1 < JT)
            bnext = __builtin_bit_cast(s16x8, sb[(jt + 1) * 64 + lane]);

        // 4 independent MFMA -> min-tree chains (named scalars, rule #20).
        f32x16 c0 = __builtin_amdgcn_mfma_f32_32x32x16_bf16(afr[0], bfr, zc, 0, 0, 0);
        f32x16 c1 = __builtin_amdgcn_mfma_f32_32x32x16_bf16(afr[1], bfr, zc, 0, 0, 0);
        f32x16 c2 = __builtin_amdgcn_mfma_f32_32x32x16_bf16(afr[2], bfr, zc, 0, 0, 0);
        f32x16 c3 = __builtin_amdgcn_mfma_f32_32x32x16_bf16(afr[3], bfr, zc, 0, 0, 0);

        float m0, m1, m2, m3;
        {
            float u0 = fminf(fminf(c0[0], c0[1]), c0[2]);
            float u1 = fminf(fminf(c0[3], c0[4]), c0[5]);
            float u2 = fminf(fminf(c0[6], c0[7]), c0[8]);
            float u3 = fminf(fminf(c0[9], c0[10]), c0[11]);
            float u4 = fminf(fminf(c0[12], c0[13]), c0[14]);
            m0 = fminf(fminf(u0, u1), fminf(fminf(u2, u3), fminf(u4, c0[15])));
        }
        {
            float u0 = fminf(fminf(c1[0], c1[1]), c1[2]);
            float u1 = fminf(fminf(c1[3], c1[4]), c1[5]);
            float u2 = fminf(fminf(c1[6], c1[7]), c1[8]);
            float u3 = fminf(fminf(c1[9], c1[10]), c1[11]);
            float u4 = fminf(fminf(c1[12], c1[13]), c1[14]);
            m1 = fminf(fminf(u0, u1), fminf(fminf(u2, u3), fminf(u4, c1[15])));
        }
        {
            float u0 = fminf(fminf(c2[0], c2[1]), c2[2]);
            float u1 = fminf(fminf(c2[3], c2[4]), c2[5]);
            float u2 = fminf(fminf(c2[6], c2[7]), c2[8]);
            float u3 = fminf(fminf(c2[9], c2[10]), c2[11]);
            float u4 = fminf(fminf(c2[12], c2[13]), c2[14]);
            m2 = fminf(fminf(u0, u1), fminf(fminf(u2, u3), fminf(u4, c2[15])));
        }
        {
            float u0 = fminf(fminf(c3[0], c3[1]), c3[2]);
            float u1 = fminf(fminf(c3[3], c3[4]), c3[5]);
            float u2 = fminf(fminf(c3[6], c3[7]), c3[8]);
            float u3 = fminf(fminf(c3[9], c3[10]), c3[11]);
            float u4 = fminf(fminf(c3[12], c3[13]), c3[14]);
            m3 = fminf(fminf(u0, u1), fminf(fminf(u2, u3), fminf(u4, c3[15])));
        }
        float acc = fminf(fminf(m0, m1), fminf(m2, m3));   // min over 64 rows
        scm[srow][jt * 32 + scol] = acc;   // fire-and-forget, bank-clean
    }
    __syncthreads();

    // Fold 8 half-wave partials -> 256 col-mins over this block's 512 rows.
    {
        int col = threadIdx.x;             // [0,256)
        float v = scm[0][col];
#pragma unroll
        for (int q = 1; q < 8; ++q) v = fminf(v, scm[q][col]);
        part[(((size_t)dir * B + b) * IGR + is4) * N + js * (JT * 32) + col] = f2bf(v);
    }
}

// 256 blocks: seg = bk>>5; min over 16 i-groups -> block sum/max partials.
__global__ __launch_bounds__(256) void reduce1(
        const unsigned short* __restrict__ part,
        float* __restrict__ bsum, float* __restrict__ bmax) {
    int bk  = blockIdx.x;
    int seg = bk >> 5;                 // 0..7
    int idx = (bk & 31) * 256 + threadIdx.x;
    const unsigned short* base = part + (size_t)seg * IGR * N + idx;
    float v = FLT_MAX;
#pragma unroll
    for (int s = 0; s < IGR; ++s)
        v = fminf(v, bf2f(base[(size_t)s * N]));
    __shared__ float ssum[256], smax[256];
    ssum[threadIdx.x] = v;
    smax[threadIdx.x] = v;
    __syncthreads();
    for (int st = 128; st > 0; st >>= 1) {
        if (threadIdx.x < st) {
            ssum[threadIdx.x] += ssum[threadIdx.x + st];
            smax[threadIdx.x] = fmaxf(smax[threadIdx.x], smax[threadIdx.x + st]);
        }
        __syncthreads();
    }
    if (threadIdx.x == 0) { bsum[bk] = ssum[0]; bmax[bk] = smax[0]; }
}

// Combine 256 block partials. Blocks [seg*32, seg*32+32) belong to segment seg.
__global__ __launch_bounds__(256) void final_combine(
        const float* __restrict__ bsum, const float* __restrict__ bmax,
        float* __restrict__ out) {
    int t = threadIdx.x;
    __shared__ float ss[256], sm[256];
    ss[t] = bsum[t];
    sm[t] = bmax[t];
    __syncthreads();
    for (int st = 128; st > 0; st >>= 1) {
        if (t < st) ss[t] += ss[t + st];
        __syncthreads();
    }
    for (int st = 16; st > 0; st >>= 1) {
        if ((t & 31) < st) sm[t] = fmaxf(sm[t], sm[t + st]);
        __syncthreads();
    }
    if (t == 0) {
        float hsum = 0.f;
#pragma unroll
        for (int k = 0; k < NSEG; ++k) hsum += sm[k * 32];
        out[0] = ss[0] / (float)(B * N);   // chamfer
        out[1] = hsum / (float)B;          // hausdorff
    }
}

extern "C" void kernel_launch(void* const* d_in, const int* in_sizes, int n_in,
                              void* d_out, int out_size, void* d_ws, size_t ws_size,
                              hipStream_t stream) {
    const float* pred = (const float*)d_in[0];
    const float* gt   = (const float*)d_in[1];
    float* out = (float*)d_out;

    char* p = (char*)d_ws;
    uint4* Aform = (uint4*)p;  p += (size_t)2 * B * 256 * 64 * 16;   // 2 MB
    uint4* Bform = (uint4*)p;  p += (size_t)2 * B * 256 * 64 * 16;   // 2 MB
    unsigned short* part = (unsigned short*)p;
    p += (size_t)NSEG * IGR * N * 2;                                 // 2 MB
    float* bsum = (float*)p;   p += 256 * 4;
    float* bmax = (float*)p;

    pack_kernel<<<512, 256, 0, stream>>>(pred, gt, Aform, Bform);
    // blocks: dir(2) x b(4) x is4(16) x js(32) = 4096, 4 waves each
    chamfer_mfma<<<4096, 256, 0, stream>>>(Aform, Bform, part);
    reduce1<<<256, 256, 0, stream>>>(part, bsum, bmax);
    final_combine<<<1, 256, 0, stream>>>(bsum, bmax, out);
}